// Round 1
// 653.030 us; speedup vs baseline: 1.4608x; 1.4608x over previous
//
#include <hip/hip_runtime.h>
#include <hip/hip_bf16.h>

#define NTOK 49
#define HEADS 6
#define DIM 192
#define DH 32

typedef short s8v __attribute__((ext_vector_type(8)));
typedef float f4v __attribute__((ext_vector_type(4)));

#define MFMA16(a, b, c) __builtin_amdgcn_mfma_f32_16x16x32_bf16((a), (b), (c), 0, 0, 0)

__device__ inline short f2bf(float f) {
    __hip_bfloat16 h = __float2bfloat16(f);
    return __builtin_bit_cast(short, h);
}

__device__ inline s8v ld_bf8(const float* __restrict__ p) {
    float4 f0 = *(const float4*)p;
    float4 f1 = *(const float4*)(p + 4);
    s8v r;
    r[0] = f2bf(f0.x); r[1] = f2bf(f0.y); r[2] = f2bf(f0.z); r[3] = f2bf(f0.w);
    r[4] = f2bf(f1.x); r[5] = f2bf(f1.y); r[6] = f2bf(f1.z); r[7] = f2bf(f1.w);
    return r;
}

// ============================ kernel 0: prep ================================
// qkv_w, proj_w -> bf16; biasM[h][r][c] = bias_table[rel_idx[r*49+c]*6+h] (fp32)
__global__ void prep_kernel(const float* __restrict__ qkv_w,
                            const float* __restrict__ proj_w,
                            const float* __restrict__ bias_table,
                            const int* __restrict__ rel_idx,
                            short* __restrict__ wq, short* __restrict__ wp,
                            float* __restrict__ biasM) {
    int tid = blockIdx.x * blockDim.x + threadIdx.x;
    int stride = gridDim.x * blockDim.x;
    for (int i = tid; i < 3 * DIM * DIM; i += stride) wq[i] = f2bf(qkv_w[i]);
    for (int i = tid; i < DIM * DIM; i += stride)     wp[i] = f2bf(proj_w[i]);
    for (int i = tid; i < HEADS * NTOK * NTOK; i += stride) {
        int h = i / (NTOK * NTOK), rc = i - h * (NTOK * NTOK);
        biasM[i] = bias_table[rel_idx[rc] * HEADS + h];
    }
}

// ============================ kernel 1: QKV =================================
// per window: q_ws[b][h][49][32] (scaled), k_ws same, v_ws = v^T [b][h][32][64]
// v2: per-wave output-column slab; weight strip (16 cols x K=192) hoisted into
// 24 VGPRs once per slab, reused across all 4 row tiles (4 independent MFMA
// chains). Weight fetches per block: 864 -> 216.
__global__ __launch_bounds__(512) void qkv_kernel(
    const float* __restrict__ x, const short* __restrict__ wq,
    const float* __restrict__ qkv_b,
    short* __restrict__ q_ws, short* __restrict__ k_ws, short* __restrict__ v_ws)
{
    __shared__ __align__(16) short xs[64 * 200];
    __shared__ __align__(16) short vbuf[192 * 72];   // [h*32+d][token]

    const int tid = threadIdx.x, w = tid >> 6, lane = tid & 63;
    const int quad = lane >> 4, l16 = lane & 15, b = blockIdx.x;

    {   // stage x (fp32 -> bf16), zero pad rows
        const float4* src = (const float4*)(x + (size_t)b * NTOK * DIM);
        for (int idx = tid; idx < 2352; idx += 512) {
            int n = idx / 48, c = idx % 48;
            float4 f = src[idx];
            short* dst = &xs[n * 200 + c * 4];
            dst[0] = f2bf(f.x); dst[1] = f2bf(f.y);
            dst[2] = f2bf(f.z); dst[3] = f2bf(f.w);
        }
        int* xz = (int*)xs;
        for (int i = tid; i < 1500; i += 512) xz[4900 + i] = 0;
        // zero vbuf pad tokens 49..71 (rows never written by epilogue)
        for (int i = tid; i < 192 * 23; i += 512) {
            int row = i / 23, t = 49 + i % 23;
            vbuf[row * 72 + t] = 0;
        }
    }
    __syncthreads();

    for (int nt = w; nt < 36; nt += 8) {            // 36 col-slabs of 16
        const short* wrow = wq + (nt * 16 + l16) * DIM + quad * 8;
        s8v bw[6];
#pragma unroll
        for (int kb = 0; kb < 6; ++kb)
            bw[kb] = *(const s8v*)(wrow + kb * 32);

        f4v acc[4];
#pragma unroll
        for (int mt = 0; mt < 4; ++mt) acc[mt] = (f4v){0.f, 0.f, 0.f, 0.f};

#pragma unroll
        for (int kb = 0; kb < 6; ++kb) {
#pragma unroll
            for (int mt = 0; mt < 4; ++mt) {
                s8v a = *(const s8v*)&xs[(mt * 16 + l16) * 200 + kb * 32 + quad * 8];
                acc[mt] = MFMA16(a, bw[kb], acc[mt]);
            }
        }

        int t = nt / 12, hh = (nt % 12) >> 1, dh16 = (nt & 1) * 16;
        float bias = qkv_b[nt * 16 + l16];
        if (t == 2) {
            short* dst = &vbuf[(hh * DH + dh16 + l16) * 72];
#pragma unroll
            for (int mt = 0; mt < 4; ++mt)
#pragma unroll
                for (int r = 0; r < 4; ++r) {
                    int row = mt * 16 + quad * 4 + r;
                    if (row < NTOK) dst[row] = f2bf(acc[mt][r] + bias);
                }
        } else {
            float scale = (t == 0) ? 0.17677669529663689f : 1.0f;
            short* dst = (t == 0 ? q_ws : k_ws)
                       + (size_t)(b * HEADS + hh) * NTOK * DH + dh16 + l16;
#pragma unroll
            for (int mt = 0; mt < 4; ++mt)
#pragma unroll
                for (int r = 0; r < 4; ++r) {
                    int row = mt * 16 + quad * 4 + r;
                    if (row < NTOK) dst[row * DH] = f2bf((acc[mt][r] + bias) * scale);
                }
        }
    }
    __syncthreads();

    {   // cooperative v^T store: 192 rows x 64 tokens, 16B chunks
        short* dstbase = v_ws + (size_t)b * 192 * 64;
        for (int c = tid; c < 1536; c += 512) {
            int row = c >> 3, tk = (c & 7) * 8;
            *(int4*)(dstbase + row * 64 + tk) = *(const int4*)&vbuf[row * 72 + tk];
        }
    }
}

// ============================ kernel 2: attention ===========================
// block = window, wave = head; one barrier (before O overwrites q region)
__global__ __launch_bounds__(384) void attn_kernel(
    const short* __restrict__ k_ws, const short* __restrict__ v_ws,
    const float* __restrict__ biasM, short* qo_ws /* q in, O out (aliased) */)
{
    __shared__ __align__(16) short ps[6 * 64 * 72];

    const int tid = threadIdx.x, w = tid >> 6, lane = tid & 63;
    const int quad = lane >> 4, l16 = lane & 15, b = blockIdx.x;
    const int h = w;
    short* psw = ps + w * 4608;

    const short* qb = qo_ws + (size_t)(b * HEADS + h) * NTOK * DH;
    const short* kb = k_ws  + (size_t)(b * HEADS + h) * NTOK * DH;
    const short* vb = v_ws  + (size_t)(b * HEADS + h) * DH * 64;

    s8v aq[4], bk[4];
    for (int i = 0; i < 4; ++i)
        aq[i] = *(const s8v*)(qb + (i * 16 + l16) * DH + quad * 8);
    for (int i = 0; i < 4; ++i)
        bk[i] = *(const s8v*)(kb + (i * 16 + l16) * DH + quad * 8);

    f4v sacc[4][4];
    for (int mt = 0; mt < 4; ++mt)
        for (int nt = 0; nt < 4; ++nt)
            sacc[mt][nt] = MFMA16(aq[mt], bk[nt], ((f4v){0.f, 0.f, 0.f, 0.f}));

    const float* bmh = biasM + h * (NTOK * NTOK);
    for (int mt = 0; mt < 4; ++mt)
        for (int r = 0; r < 4; ++r) {
            int row = mt * 16 + quad * 4 + r;
            float sv[4];
            for (int nt = 0; nt < 4; ++nt) {
                int col = nt * 16 + l16;
                float s = sacc[mt][nt][r];
                if (col < NTOK) {
                    if (row < NTOK) s += bmh[row * NTOK + col];
                } else s = -30000.f;
                sv[nt] = s;
            }
            float m = fmaxf(fmaxf(sv[0], sv[1]), fmaxf(sv[2], sv[3]));
            for (int d = 1; d < 16; d <<= 1) m = fmaxf(m, __shfl_xor(m, d));
            float p[4], sum = 0.f;
            for (int nt = 0; nt < 4; ++nt) {
                p[nt] = exp2f((sv[nt] - m) * 1.4426950408889634f);
                sum += p[nt];
            }
            for (int d = 1; d < 16; d <<= 1) sum += __shfl_xor(sum, d);
            float inv = 1.f / sum;
            for (int nt = 0; nt < 4; ++nt)
                psw[row * 72 + nt * 16 + l16] = f2bf(p[nt] * inv);
        }

    f4v oacc[4][2];
    for (int mt = 0; mt < 4; ++mt)
        for (int nv = 0; nv < 2; ++nv) oacc[mt][nv] = (f4v){0.f, 0.f, 0.f, 0.f};
    for (int ks = 0; ks < 2; ++ks) {
        s8v bv[2];
        for (int nv = 0; nv < 2; ++nv)
            bv[nv] = *(const s8v*)(vb + (nv * 16 + l16) * 64 + ks * 32 + quad * 8);
        for (int mt = 0; mt < 4; ++mt) {
            s8v ap = *(const s8v*)&psw[(mt * 16 + l16) * 72 + ks * 32 + quad * 8];
            for (int nv = 0; nv < 2; ++nv)
                oacc[mt][nv] = MFMA16(ap, bv[nv], oacc[mt][nv]);
        }
    }

    __syncthreads();   // all q/k/v global reads done before O overwrites q region

    for (int mt = 0; mt < 4; ++mt)
        for (int nv = 0; nv < 2; ++nv)
            for (int r = 0; r < 4; ++r) {
                int row = mt * 16 + quad * 4 + r;
                if (row < NTOK)
                    qo_ws[((size_t)(b * NTOK + row) * HEADS + h) * DH + nv * 16 + l16] =
                        f2bf(oacc[mt][nv][r]);
            }
}

// ============================ kernel 3: proj ================================
// v2: 256 threads (4 waves), 12 col-slabs -> 3 balanced slabs/wave; weight
// strip hoisted into registers per slab, reused across 4 row tiles.
__global__ __launch_bounds__(256) void proj_kernel(
    const short* __restrict__ o_ws, const short* __restrict__ wp,
    const float* __restrict__ proj_b, float* __restrict__ out)
{
    __shared__ __align__(16) short os[64 * 200];
    const int tid = threadIdx.x, w = tid >> 6, lane = tid & 63;
    const int quad = lane >> 4, l16 = lane & 15, b = blockIdx.x;

    {
        const short* src = o_ws + (size_t)b * NTOK * DIM;
        for (int c = tid; c < 1176; c += 256) {
            int n = c / 24, cc = (c % 24) * 8;
            *(int4*)&os[n * 200 + cc] = *(const int4*)(src + n * DIM + cc);
        }
        int* oz = (int*)os;
        for (int i = tid; i < 1500; i += 256) oz[4900 + i] = 0;
    }
    __syncthreads();

    for (int nt = w; nt < 12; nt += 4) {
        const short* wrow = wp + (nt * 16 + l16) * DIM + quad * 8;
        s8v bw[6];
#pragma unroll
        for (int kb = 0; kb < 6; ++kb)
            bw[kb] = *(const s8v*)(wrow + kb * 32);

        f4v acc[4];
#pragma unroll
        for (int mt = 0; mt < 4; ++mt) acc[mt] = (f4v){0.f, 0.f, 0.f, 0.f};

#pragma unroll
        for (int kb = 0; kb < 6; ++kb) {
#pragma unroll
            for (int mt = 0; mt < 4; ++mt) {
                s8v a = *(const s8v*)&os[(mt * 16 + l16) * 200 + kb * 32 + quad * 8];
                acc[mt] = MFMA16(a, bw[kb], acc[mt]);
            }
        }

        int j0 = nt * 16 + l16;
        float bias = proj_b[j0];
        float* dst = out + (size_t)b * NTOK * DIM + j0;
#pragma unroll
        for (int mt = 0; mt < 4; ++mt)
#pragma unroll
            for (int r = 0; r < 4; ++r) {
                int row = mt * 16 + quad * 4 + r;
                if (row < NTOK) dst[row * DIM] = acc[mt][r] + bias;
            }
    }
}

// ===================== fallback: round-2 fused kernel =======================
__global__ __launch_bounds__(512) void winattn_fused(
    const float* __restrict__ x, const float* __restrict__ qkv_w,
    const float* __restrict__ qkv_b, const float* __restrict__ proj_w,
    const float* __restrict__ proj_b, const float* __restrict__ bias_table,
    const int* __restrict__ rel_idx, float* __restrict__ out)
{
    __shared__ __align__(16) short xs[64 * 200];
    __shared__ __align__(16) short qs[64 * 40];
    __shared__ __align__(16) short ks[64 * 40];
    __shared__ __align__(16) short vs[32 * 72];
    __shared__ __align__(16) short pp[64 * 72];

    const int tid = threadIdx.x, w = tid >> 6, lane = tid & 63;
    const int quad = lane >> 4, l16 = lane & 15, b = blockIdx.x;
    const int mt = w & 3, half = w >> 2;

    {
        const float4* src = (const float4*)(x + (size_t)b * NTOK * DIM);
        for (int idx = tid; idx < 2352; idx += 512) {
            int n = idx / 48, c = idx % 48;
            float4 f = src[idx];
            short* dst = &xs[n * 200 + c * 4];
            dst[0] = f2bf(f.x); dst[1] = f2bf(f.y);
            dst[2] = f2bf(f.z); dst[3] = f2bf(f.w);
        }
        int* xz = (int*)xs;
        for (int i = tid; i < 1500; i += 512) xz[4900 + i] = 0;
    }
    __syncthreads();

    f4v acc_p[6];
    for (int i = 0; i < 6; i++) acc_p[i] = (f4v){0.f, 0.f, 0.f, 0.f};

    for (int h = 0; h < HEADS; ++h) {
        {
            f4v acc[3];
            for (int i = 0; i < 3; i++) acc[i] = (f4v){0.f, 0.f, 0.f, 0.f};
            int jbase[3];
            for (int i = 0; i < 3; i++) {
                int tn = half * 3 + i;
                int t = tn >> 1, dpart = (tn & 1) * 16;
                jbase[i] = t * DIM + h * DH + dpart + l16;
            }
            for (int kb2 = 0; kb2 < 6; ++kb2) {
                s8v a = *(const s8v*)&xs[(mt * 16 + l16) * 200 + kb2 * 32 + quad * 8];
                for (int i = 0; i < 3; i++) {
                    s8v bf = ld_bf8(qkv_w + jbase[i] * DIM + kb2 * 32 + quad * 8);
                    acc[i] = MFMA16(a, bf, acc[i]);
                }
            }
            for (int i = 0; i < 3; i++) {
                int tn = half * 3 + i;
                int t = tn >> 1, dpart = (tn & 1) * 16;
                float bias = qkv_b[jbase[i]];
                for (int r = 0; r < 4; r++) {
                    int row = mt * 16 + quad * 4 + r;
                    float v = acc[i][r] + bias;
                    if (t == 0)      qs[row * 40 + dpart + l16] = f2bf(v * 0.17677669529663689f);
                    else if (t == 1) ks[row * 40 + dpart + l16] = f2bf(v);
                    else             vs[(dpart + l16) * 72 + row] = f2bf(v);
                }
            }
        }
        __syncthreads();
        if (w < 4) {
            f4v sacc[4];
            for (int i = 0; i < 4; i++) sacc[i] = (f4v){0.f, 0.f, 0.f, 0.f};
            s8v a = *(const s8v*)&qs[(w * 16 + l16) * 40 + quad * 8];
            for (int nt = 0; nt < 4; nt++) {
                s8v bf = *(const s8v*)&ks[(nt * 16 + l16) * 40 + quad * 8];
                sacc[nt] = MFMA16(a, bf, sacc[nt]);
            }
            for (int r = 0; r < 4; r++) {
                int row = w * 16 + quad * 4 + r;
                float sv[4];
                for (int nt = 0; nt < 4; nt++) {
                    int col = nt * 16 + l16;
                    float s = sacc[nt][r];
                    if (col < NTOK) {
                        if (row < NTOK)
                            s += bias_table[rel_idx[row * NTOK + col] * HEADS + h];
                    } else s = -30000.f;
                    sv[nt] = s;
                }
                float m = fmaxf(fmaxf(sv[0], sv[1]), fmaxf(sv[2], sv[3]));
                for (int d = 1; d < 16; d <<= 1) m = fmaxf(m, __shfl_xor(m, d));
                float p[4], sum = 0.f;
                for (int nt = 0; nt < 4; nt++) {
                    p[nt] = exp2f((sv[nt] - m) * 1.4426950408889634f);
                    sum += p[nt];
                }
                for (int d = 1; d < 16; d <<= 1) sum += __shfl_xor(sum, d);
                float inv = 1.f / sum;
                for (int nt = 0; nt < 4; nt++)
                    pp[row * 72 + nt * 16 + l16] = f2bf(p[nt] * inv);
            }
        }
        __syncthreads();
        {
            f4v oacc = (f4v){0.f, 0.f, 0.f, 0.f};
            for (int kb2 = 0; kb2 < 2; kb2++) {
                s8v a  = *(const s8v*)&pp[(mt * 16 + l16) * 72 + kb2 * 32 + quad * 8];
                s8v bf = *(const s8v*)&vs[(half * 16 + l16) * 72 + kb2 * 32 + quad * 8];
                oacc = MFMA16(a, bf, oacc);
            }
            for (int r = 0; r < 4; r++) {
                int row = mt * 16 + quad * 4 + r;
                qs[row * 40 + half * 16 + l16] = f2bf(oacc[r]);
            }
        }
        __syncthreads();
        {
            s8v a = *(const s8v*)&qs[(mt * 16 + l16) * 40 + quad * 8];
            for (int i = 0; i < 6; i++) {
                int ncol = half * 96 + i * 16 + l16;
                s8v bf = ld_bf8(proj_w + ncol * DIM + h * DH + quad * 8);
                acc_p[i] = MFMA16(a, bf, acc_p[i]);
            }
        }
        __syncthreads();
    }
    for (int i = 0; i < 6; i++) {
        int ncol = half * 96 + i * 16 + l16;
        float bias = proj_b[ncol];
        for (int r = 0; r < 4; r++) {
            int row = mt * 16 + quad * 4 + r;
            if (row < NTOK)
                out[((size_t)b * NTOK + row) * DIM + ncol] = acc_p[i][r] + bias;
        }
    }
}

// ============================================================================
extern "C" void kernel_launch(void* const* d_in, const int* in_sizes, int n_in,
                              void* d_out, int out_size, void* d_ws, size_t ws_size,
                              hipStream_t stream) {
    const float* x          = (const float*)d_in[0];
    const float* qkv_w      = (const float*)d_in[1];
    const float* qkv_b      = (const float*)d_in[2];
    const float* proj_w     = (const float*)d_in[3];
    const float* proj_b     = (const float*)d_in[4];
    const float* bias_table = (const float*)d_in[5];
    const int*   rel_idx    = (const int*)d_in[6];
    float*       out        = (float*)d_out;

    const int B_ = in_sizes[0] / (NTOK * DIM);   // 4096

    // workspace layout (bytes)
    const size_t sz_q  = (size_t)B_ * HEADS * NTOK * DH * 2;   // q / O aliased
    const size_t sz_k  = sz_q;
    const size_t sz_v  = (size_t)B_ * HEADS * DH * 64 * 2;     // v^T padded to 64
    const size_t sz_wq = (size_t)3 * DIM * DIM * 2;
    const size_t sz_wp = (size_t)DIM * DIM * 2;
    const size_t sz_bm = (size_t)HEADS * NTOK * NTOK * 4;
    const size_t need  = sz_q + sz_k + sz_v + sz_wq + sz_wp + sz_bm;

    if (ws_size >= need) {
        char* p = (char*)d_ws;
        short* q_ws  = (short*)p;                 p += sz_q;
        short* k_ws  = (short*)p;                 p += sz_k;
        short* v_ws  = (short*)p;                 p += sz_v;
        short* wq    = (short*)p;                 p += sz_wq;
        short* wp    = (short*)p;                 p += sz_wp;
        float* biasM = (float*)p;

        prep_kernel<<<dim3(128), dim3(256), 0, stream>>>(
            qkv_w, proj_w, bias_table, rel_idx, wq, wp, biasM);
        qkv_kernel<<<dim3(B_), dim3(512), 0, stream>>>(
            x, wq, qkv_b, q_ws, k_ws, v_ws);
        attn_kernel<<<dim3(B_), dim3(384), 0, stream>>>(
            k_ws, v_ws, biasM, q_ws);
        proj_kernel<<<dim3(B_), dim3(256), 0, stream>>>(
            q_ws, wp, proj_b, out);
    } else {
        winattn_fused<<<dim3(B_), dim3(512), 0, stream>>>(
            x, qkv_w, qkv_b, proj_w, proj_b, bias_table, rel_idx, out);
    }
}

// Round 3
// 575.080 us; speedup vs baseline: 1.6588x; 1.1355x over previous
//
#include <hip/hip_runtime.h>
#include <hip/hip_bf16.h>

#define NTOK 49
#define HEADS 6
#define DIM 192
#define DH 32

typedef short s8v __attribute__((ext_vector_type(8)));
typedef float f4v __attribute__((ext_vector_type(4)));

#define MFMA16(a, b, c) __builtin_amdgcn_mfma_f32_16x16x32_bf16((a), (b), (c), 0, 0, 0)

__device__ inline short f2bf(float f) {
    __hip_bfloat16 h = __float2bfloat16(f);
    return __builtin_bit_cast(short, h);
}

__device__ inline s8v ld_bf8(const float* __restrict__ p) {
    float4 f0 = *(const float4*)p;
    float4 f1 = *(const float4*)(p + 4);
    s8v r;
    r[0] = f2bf(f0.x); r[1] = f2bf(f0.y); r[2] = f2bf(f0.z); r[3] = f2bf(f0.w);
    r[4] = f2bf(f1.x); r[5] = f2bf(f1.y); r[6] = f2bf(f1.z); r[7] = f2bf(f1.w);
    return r;
}

// ============================ kernel 0: prep ================================
// qkv_w, proj_w -> bf16; biasM[h][r][c] = bias_table[rel_idx[r*49+c]*6+h] (fp32)
__global__ void prep_kernel(const float* __restrict__ qkv_w,
                            const float* __restrict__ proj_w,
                            const float* __restrict__ bias_table,
                            const int* __restrict__ rel_idx,
                            short* __restrict__ wq, short* __restrict__ wp,
                            float* __restrict__ biasM) {
    int tid = blockIdx.x * blockDim.x + threadIdx.x;
    int stride = gridDim.x * blockDim.x;
    for (int i = tid; i < 3 * DIM * DIM; i += stride) wq[i] = f2bf(qkv_w[i]);
    for (int i = tid; i < DIM * DIM; i += stride)     wp[i] = f2bf(proj_w[i]);
    for (int i = tid; i < HEADS * NTOK * NTOK; i += stride) {
        int h = i / (NTOK * NTOK), rc = i - h * (NTOK * NTOK);
        biasM[i] = bias_table[rel_idx[rc] * HEADS + h];
    }
}

// ===================== fused qkv+attn+proj (one block = one window) =========
// LDS plan (159744 B total, dynamic):
//   xs  [64][200] bf16  x staged       (reused as os [64][200] for O)
//   qs  [64][200] bf16  q scaled, cols h*32+d
//   ks  [64][200] bf16  k,             cols h*32+d
//   vs  [192][72] bf16  v^T  (row = h*32+d, col = token)
//   ps  6 x [64][72]    per-head-wave P
// 3 barriers: after stage, after qkv writes, after O writes.
__global__ __launch_bounds__(512) void fused3(
    const float* __restrict__ x, const short* __restrict__ wq,
    const float* __restrict__ qkv_b, const short* __restrict__ wp,
    const float* __restrict__ proj_b, const float* __restrict__ biasM,
    float* __restrict__ out)
{
    extern __shared__ __align__(16) short smem[];
    short* xs = smem;              // 12800 shorts (also os)
    short* qs = smem + 12800;      // 12800
    short* ks = smem + 25600;      // 12800
    short* vs = smem + 38400;      // 13824
    short* ps = smem + 52224;      // 27648

    const int tid = threadIdx.x, w = tid >> 6, lane = tid & 63;
    const int quad = lane >> 4, l16 = lane & 15, b = blockIdx.x;

    {   // stage x (fp32 -> bf16), zero pad rows 49..63
        const float4* src = (const float4*)(x + (size_t)b * NTOK * DIM);
        for (int idx = tid; idx < 2352; idx += 512) {
            int n = idx / 48, c = idx % 48;
            float4 f = src[idx];
            short* dst = &xs[n * 200 + c * 4];
            dst[0] = f2bf(f.x); dst[1] = f2bf(f.y);
            dst[2] = f2bf(f.z); dst[3] = f2bf(f.w);
        }
        int* xz = (int*)xs;
        for (int i = tid; i < 1500; i += 512) xz[4900 + i] = 0;
    }
    __syncthreads();

    // ---------------- QKV: 36 col-slabs of 16, weights reg-hoisted ----------
    for (int nt = w; nt < 36; nt += 8) {
        const short* wrow = wq + (nt * 16 + l16) * DIM + quad * 8;
        s8v bw[6];
#pragma unroll
        for (int kb = 0; kb < 6; ++kb)
            bw[kb] = *(const s8v*)(wrow + kb * 32);

        f4v acc[4];
#pragma unroll
        for (int mt = 0; mt < 4; ++mt) acc[mt] = (f4v){0.f, 0.f, 0.f, 0.f};

#pragma unroll
        for (int kb = 0; kb < 6; ++kb) {
#pragma unroll
            for (int mt = 0; mt < 4; ++mt) {
                s8v a = *(const s8v*)&xs[(mt * 16 + l16) * 200 + kb * 32 + quad * 8];
                acc[mt] = MFMA16(a, bw[kb], acc[mt]);
            }
        }

        int t = nt / 12, hh = (nt % 12) >> 1, dh16 = (nt & 1) * 16;
        float bias = qkv_b[nt * 16 + l16];
        if (t == 2) {
            short* dst = &vs[(hh * DH + dh16 + l16) * 72];
#pragma unroll
            for (int mt = 0; mt < 4; ++mt)
#pragma unroll
                for (int r = 0; r < 4; ++r) {
                    int row = mt * 16 + quad * 4 + r;
                    dst[row] = f2bf(acc[mt][r] + bias);   // pad tokens = finite bias
                }
        } else {
            float scale = (t == 0) ? 0.17677669529663689f : 1.0f;
            short* dst = (t == 0 ? qs : ks) + hh * DH + dh16 + l16;
#pragma unroll
            for (int mt = 0; mt < 4; ++mt)
#pragma unroll
                for (int r = 0; r < 4; ++r) {
                    int row = mt * 16 + quad * 4 + r;
                    dst[row * 200] = f2bf((acc[mt][r] + bias) * scale);
                }
        }
    }
    __syncthreads();

    // ---------------- attention: wave = head (waves 0..5) -------------------
    if (w < HEADS) {
        const int h = w;
        short* psw = ps + w * 4608;

        s8v aq[4], bk[4];
#pragma unroll
        for (int i = 0; i < 4; ++i)
            aq[i] = *(const s8v*)&qs[(i * 16 + l16) * 200 + h * DH + quad * 8];
#pragma unroll
        for (int i = 0; i < 4; ++i)
            bk[i] = *(const s8v*)&ks[(i * 16 + l16) * 200 + h * DH + quad * 8];

        f4v sacc[4][4];
#pragma unroll
        for (int mt = 0; mt < 4; ++mt)
#pragma unroll
            for (int nt = 0; nt < 4; ++nt)
                sacc[mt][nt] = MFMA16(aq[mt], bk[nt], ((f4v){0.f, 0.f, 0.f, 0.f}));

        const float* bmh = biasM + h * (NTOK * NTOK);
#pragma unroll
        for (int mt = 0; mt < 4; ++mt)
            for (int r = 0; r < 4; ++r) {
                int row = mt * 16 + quad * 4 + r;
                float sv[4];
#pragma unroll
                for (int nt = 0; nt < 4; ++nt) {
                    int col = nt * 16 + l16;
                    float s = sacc[mt][nt][r];
                    if (col < NTOK) {
                        if (row < NTOK) s += bmh[row * NTOK + col];
                    } else s = -30000.f;
                    sv[nt] = s;
                }
                float m = fmaxf(fmaxf(sv[0], sv[1]), fmaxf(sv[2], sv[3]));
                for (int d = 1; d < 16; d <<= 1) m = fmaxf(m, __shfl_xor(m, d));
                float p[4], sum = 0.f;
#pragma unroll
                for (int nt = 0; nt < 4; ++nt) {
                    p[nt] = exp2f((sv[nt] - m) * 1.4426950408889634f);
                    sum += p[nt];
                }
                for (int d = 1; d < 16; d <<= 1) sum += __shfl_xor(sum, d);
                float inv = 1.f / sum;
#pragma unroll
                for (int nt = 0; nt < 4; ++nt)
                    psw[row * 72 + nt * 16 + l16] = f2bf(p[nt] * inv);
            }

        f4v oacc[4][2];
#pragma unroll
        for (int mt = 0; mt < 4; ++mt)
#pragma unroll
            for (int nv = 0; nv < 2; ++nv) oacc[mt][nv] = (f4v){0.f, 0.f, 0.f, 0.f};
#pragma unroll
        for (int ks2 = 0; ks2 < 2; ++ks2) {
            s8v bv[2];
#pragma unroll
            for (int nv = 0; nv < 2; ++nv)
                bv[nv] = *(const s8v*)&vs[(h * DH + nv * 16 + l16) * 72 + ks2 * 32 + quad * 8];
#pragma unroll
            for (int mt = 0; mt < 4; ++mt) {
                s8v ap = *(const s8v*)&psw[(mt * 16 + l16) * 72 + ks2 * 32 + quad * 8];
#pragma unroll
                for (int nv = 0; nv < 2; ++nv)
                    oacc[mt][nv] = MFMA16(ap, bv[nv], oacc[mt][nv]);
            }
        }

        // O -> os (overlays xs; xs dead since barrier 2)
        short* os = xs;
#pragma unroll
        for (int mt = 0; mt < 4; ++mt)
#pragma unroll
            for (int nv = 0; nv < 2; ++nv)
#pragma unroll
                for (int r = 0; r < 4; ++r) {
                    int row = mt * 16 + quad * 4 + r;
                    os[row * 200 + h * DH + nv * 16 + l16] = f2bf(oacc[mt][nv][r]);
                }
    }
    __syncthreads();

    // ---------------- proj: 12 col-slabs of 16 ------------------------------
    for (int nt = w; nt < 12; nt += 8) {
        const short* wrow = wp + (nt * 16 + l16) * DIM + quad * 8;
        s8v bw[6];
#pragma unroll
        for (int kb = 0; kb < 6; ++kb)
            bw[kb] = *(const s8v*)(wrow + kb * 32);

        f4v acc[4];
#pragma unroll
        for (int mt = 0; mt < 4; ++mt) acc[mt] = (f4v){0.f, 0.f, 0.f, 0.f};

#pragma unroll
        for (int kb = 0; kb < 6; ++kb) {
#pragma unroll
            for (int mt = 0; mt < 4; ++mt) {
                s8v a = *(const s8v*)&xs[(mt * 16 + l16) * 200 + kb * 32 + quad * 8];
                acc[mt] = MFMA16(a, bw[kb], acc[mt]);
            }
        }

        int j0 = nt * 16 + l16;
        float bias = proj_b[j0];
        float* dst = out + (size_t)b * NTOK * DIM + j0;
#pragma unroll
        for (int mt = 0; mt < 4; ++mt)
#pragma unroll
            for (int r = 0; r < 4; ++r) {
                int row = mt * 16 + quad * 4 + r;
                if (row < NTOK) dst[row * DIM] = acc[mt][r] + bias;
            }
    }
}

// ===================== split-path kernels (fallback) ========================
__global__ __launch_bounds__(512) void qkv_kernel(
    const float* __restrict__ x, const short* __restrict__ wq,
    const float* __restrict__ qkv_b,
    short* __restrict__ q_ws, short* __restrict__ k_ws, short* __restrict__ v_ws)
{
    __shared__ __align__(16) short xs[64 * 200];
    __shared__ __align__(16) short vbuf[192 * 72];

    const int tid = threadIdx.x, w = tid >> 6, lane = tid & 63;
    const int quad = lane >> 4, l16 = lane & 15, b = blockIdx.x;

    {
        const float4* src = (const float4*)(x + (size_t)b * NTOK * DIM);
        for (int idx = tid; idx < 2352; idx += 512) {
            int n = idx / 48, c = idx % 48;
            float4 f = src[idx];
            short* dst = &xs[n * 200 + c * 4];
            dst[0] = f2bf(f.x); dst[1] = f2bf(f.y);
            dst[2] = f2bf(f.z); dst[3] = f2bf(f.w);
        }
        int* xz = (int*)xs;
        for (int i = tid; i < 1500; i += 512) xz[4900 + i] = 0;
        for (int i = tid; i < 192 * 23; i += 512) {
            int row = i / 23, t = 49 + i % 23;
            vbuf[row * 72 + t] = 0;
        }
    }
    __syncthreads();

    for (int nt = w; nt < 36; nt += 8) {
        const short* wrow = wq + (nt * 16 + l16) * DIM + quad * 8;
        s8v bw[6];
#pragma unroll
        for (int kb = 0; kb < 6; ++kb) bw[kb] = *(const s8v*)(wrow + kb * 32);
        f4v acc[4];
#pragma unroll
        for (int mt = 0; mt < 4; ++mt) acc[mt] = (f4v){0.f, 0.f, 0.f, 0.f};
#pragma unroll
        for (int kb = 0; kb < 6; ++kb)
#pragma unroll
            for (int mt = 0; mt < 4; ++mt) {
                s8v a = *(const s8v*)&xs[(mt * 16 + l16) * 200 + kb * 32 + quad * 8];
                acc[mt] = MFMA16(a, bw[kb], acc[mt]);
            }
        int t = nt / 12, hh = (nt % 12) >> 1, dh16 = (nt & 1) * 16;
        float bias = qkv_b[nt * 16 + l16];
        if (t == 2) {
            short* dst = &vbuf[(hh * DH + dh16 + l16) * 72];
#pragma unroll
            for (int mt = 0; mt < 4; ++mt)
#pragma unroll
                for (int r = 0; r < 4; ++r) {
                    int row = mt * 16 + quad * 4 + r;
                    if (row < NTOK) dst[row] = f2bf(acc[mt][r] + bias);
                }
        } else {
            float scale = (t == 0) ? 0.17677669529663689f : 1.0f;
            short* dst = (t == 0 ? q_ws : k_ws)
                       + (size_t)(b * HEADS + hh) * NTOK * DH + dh16 + l16;
#pragma unroll
            for (int mt = 0; mt < 4; ++mt)
#pragma unroll
                for (int r = 0; r < 4; ++r) {
                    int row = mt * 16 + quad * 4 + r;
                    if (row < NTOK) dst[row * DH] = f2bf((acc[mt][r] + bias) * scale);
                }
        }
    }
    __syncthreads();

    {
        short* dstbase = v_ws + (size_t)b * 192 * 64;
        for (int c = tid; c < 1536; c += 512) {
            int row = c >> 3, tk = (c & 7) * 8;
            *(int4*)(dstbase + row * 64 + tk) = *(const int4*)&vbuf[row * 72 + tk];
        }
    }
}

__global__ __launch_bounds__(384) void attn_kernel(
    const short* __restrict__ k_ws, const short* __restrict__ v_ws,
    const float* __restrict__ biasM, short* qo_ws)
{
    __shared__ __align__(16) short ps[6 * 64 * 72];

    const int tid = threadIdx.x, w = tid >> 6, lane = tid & 63;
    const int quad = lane >> 4, l16 = lane & 15, b = blockIdx.x;
    const int h = w;
    short* psw = ps + w * 4608;

    const short* qb = qo_ws + (size_t)(b * HEADS + h) * NTOK * DH;
    const short* kb = k_ws  + (size_t)(b * HEADS + h) * NTOK * DH;
    const short* vb = v_ws  + (size_t)(b * HEADS + h) * DH * 64;

    s8v aq[4], bk[4];
    for (int i = 0; i < 4; ++i)
        aq[i] = *(const s8v*)(qb + (i * 16 + l16) * DH + quad * 8);
    for (int i = 0; i < 4; ++i)
        bk[i] = *(const s8v*)(kb + (i * 16 + l16) * DH + quad * 8);

    f4v sacc[4][4];
    for (int mt = 0; mt < 4; ++mt)
        for (int nt = 0; nt < 4; ++nt)
            sacc[mt][nt] = MFMA16(aq[mt], bk[nt], ((f4v){0.f, 0.f, 0.f, 0.f}));

    const float* bmh = biasM + h * (NTOK * NTOK);
    for (int mt = 0; mt < 4; ++mt)
        for (int r = 0; r < 4; ++r) {
            int row = mt * 16 + quad * 4 + r;
            float sv[4];
            for (int nt = 0; nt < 4; ++nt) {
                int col = nt * 16 + l16;
                float s = sacc[mt][nt][r];
                if (col < NTOK) {
                    if (row < NTOK) s += bmh[row * NTOK + col];
                } else s = -30000.f;
                sv[nt] = s;
            }
            float m = fmaxf(fmaxf(sv[0], sv[1]), fmaxf(sv[2], sv[3]));
            for (int d = 1; d < 16; d <<= 1) m = fmaxf(m, __shfl_xor(m, d));
            float p[4], sum = 0.f;
            for (int nt = 0; nt < 4; ++nt) {
                p[nt] = exp2f((sv[nt] - m) * 1.4426950408889634f);
                sum += p[nt];
            }
            for (int d = 1; d < 16; d <<= 1) sum += __shfl_xor(sum, d);
            float inv = 1.f / sum;
            for (int nt = 0; nt < 4; ++nt)
                psw[row * 72 + nt * 16 + l16] = f2bf(p[nt] * inv);
        }

    f4v oacc[4][2];
    for (int mt = 0; mt < 4; ++mt)
        for (int nv = 0; nv < 2; ++nv) oacc[mt][nv] = (f4v){0.f, 0.f, 0.f, 0.f};
    for (int ks = 0; ks < 2; ++ks) {
        s8v bv[2];
        for (int nv = 0; nv < 2; ++nv)
            bv[nv] = *(const s8v*)(vb + (nv * 16 + l16) * 64 + ks * 32 + quad * 8);
        for (int mt = 0; mt < 4; ++mt) {
            s8v ap = *(const s8v*)&psw[(mt * 16 + l16) * 72 + ks * 32 + quad * 8];
            for (int nv = 0; nv < 2; ++nv)
                oacc[mt][nv] = MFMA16(ap, bv[nv], oacc[mt][nv]);
        }
    }

    __syncthreads();

    for (int mt = 0; mt < 4; ++mt)
        for (int nv = 0; nv < 2; ++nv)
            for (int r = 0; r < 4; ++r) {
                int row = mt * 16 + quad * 4 + r;
                if (row < NTOK)
                    qo_ws[((size_t)(b * NTOK + row) * HEADS + h) * DH + nv * 16 + l16] =
                        f2bf(oacc[mt][nv][r]);
            }
}

__global__ __launch_bounds__(256) void proj_kernel(
    const short* __restrict__ o_ws, const short* __restrict__ wp,
    const float* __restrict__ proj_b, float* __restrict__ out)
{
    __shared__ __align__(16) short os[64 * 200];
    const int tid = threadIdx.x, w = tid >> 6, lane = tid & 63;
    const int quad = lane >> 4, l16 = lane & 15, b = blockIdx.x;

    {
        const short* src = o_ws + (size_t)b * NTOK * DIM;
        for (int c = tid; c < 1176; c += 256) {
            int n = c / 24, cc = (c % 24) * 8;
            *(int4*)&os[n * 200 + cc] = *(const int4*)(src + n * DIM + cc);
        }
        int* oz = (int*)os;
        for (int i = tid; i < 1500; i += 256) oz[4900 + i] = 0;
    }
    __syncthreads();

    for (int nt = w; nt < 12; nt += 4) {
        const short* wrow = wp + (nt * 16 + l16) * DIM + quad * 8;
        s8v bw[6];
#pragma unroll
        for (int kb = 0; kb < 6; ++kb) bw[kb] = *(const s8v*)(wrow + kb * 32);
        f4v acc[4];
#pragma unroll
        for (int mt = 0; mt < 4; ++mt) acc[mt] = (f4v){0.f, 0.f, 0.f, 0.f};
#pragma unroll
        for (int kb = 0; kb < 6; ++kb)
#pragma unroll
            for (int mt = 0; mt < 4; ++mt) {
                s8v a = *(const s8v*)&os[(mt * 16 + l16) * 200 + kb * 32 + quad * 8];
                acc[mt] = MFMA16(a, bw[kb], acc[mt]);
            }
        int j0 = nt * 16 + l16;
        float bias = proj_b[j0];
        float* dst = out + (size_t)b * NTOK * DIM + j0;
#pragma unroll
        for (int mt = 0; mt < 4; ++mt)
#pragma unroll
            for (int r = 0; r < 4; ++r) {
                int row = mt * 16 + quad * 4 + r;
                if (row < NTOK) dst[row * DIM] = acc[mt][r] + bias;
            }
    }
}

// ===================== fallback: round-2 fused kernel =======================
__global__ __launch_bounds__(512) void winattn_fused(
    const float* __restrict__ x, const float* __restrict__ qkv_w,
    const float* __restrict__ qkv_b, const float* __restrict__ proj_w,
    const float* __restrict__ proj_b, const float* __restrict__ bias_table,
    const int* __restrict__ rel_idx, float* __restrict__ out)
{
    __shared__ __align__(16) short xs[64 * 200];
    __shared__ __align__(16) short qs[64 * 40];
    __shared__ __align__(16) short ks[64 * 40];
    __shared__ __align__(16) short vs[32 * 72];
    __shared__ __align__(16) short pp[64 * 72];

    const int tid = threadIdx.x, w = tid >> 6, lane = tid & 63;
    const int quad = lane >> 4, l16 = lane & 15, b = blockIdx.x;
    const int mt = w & 3, half = w >> 2;

    {
        const float4* src = (const float4*)(x + (size_t)b * NTOK * DIM);
        for (int idx = tid; idx < 2352; idx += 512) {
            int n = idx / 48, c = idx % 48;
            float4 f = src[idx];
            short* dst = &xs[n * 200 + c * 4];
            dst[0] = f2bf(f.x); dst[1] = f2bf(f.y);
            dst[2] = f2bf(f.z); dst[3] = f2bf(f.w);
        }
        int* xz = (int*)xs;
        for (int i = tid; i < 1500; i += 512) xz[4900 + i] = 0;
    }
    __syncthreads();

    f4v acc_p[6];
    for (int i = 0; i < 6; i++) acc_p[i] = (f4v){0.f, 0.f, 0.f, 0.f};

    for (int h = 0; h < HEADS; ++h) {
        {
            f4v acc[3];
            for (int i = 0; i < 3; i++) acc[i] = (f4v){0.f, 0.f, 0.f, 0.f};
            int jbase[3];
            for (int i = 0; i < 3; i++) {
                int tn = half * 3 + i;
                int t = tn >> 1, dpart = (tn & 1) * 16;
                jbase[i] = t * DIM + h * DH + dpart + l16;
            }
            for (int kb2 = 0; kb2 < 6; ++kb2) {
                s8v a = *(const s8v*)&xs[(mt * 16 + l16) * 200 + kb2 * 32 + quad * 8];
                for (int i = 0; i < 3; i++) {
                    s8v bf = ld_bf8(qkv_w + jbase[i] * DIM + kb2 * 32 + quad * 8);
                    acc[i] = MFMA16(a, bf, acc[i]);
                }
            }
            for (int i = 0; i < 3; i++) {
                int tn = half * 3 + i;
                int t = tn >> 1, dpart = (tn & 1) * 16;
                float bias = qkv_b[jbase[i]];
                for (int r = 0; r < 4; r++) {
                    int row = mt * 16 + quad * 4 + r;
                    float v = acc[i][r] + bias;
                    if (t == 0)      qs[row * 40 + dpart + l16] = f2bf(v * 0.17677669529663689f);
                    else if (t == 1) ks[row * 40 + dpart + l16] = f2bf(v);
                    else             vs[(dpart + l16) * 72 + row] = f2bf(v);
                }
            }
        }
        __syncthreads();
        if (w < 4) {
            f4v sacc[4];
            for (int i = 0; i < 4; i++) sacc[i] = (f4v){0.f, 0.f, 0.f, 0.f};
            s8v a = *(const s8v*)&qs[(w * 16 + l16) * 40 + quad * 8];
            for (int nt = 0; nt < 4; nt++) {
                s8v bf = *(const s8v*)&ks[(nt * 16 + l16) * 40 + quad * 8];
                sacc[nt] = MFMA16(a, bf, sacc[nt]);
            }
            for (int r = 0; r < 4; r++) {
                int row = w * 16 + quad * 4 + r;
                float sv[4];
                for (int nt = 0; nt < 4; nt++) {
                    int col = nt * 16 + l16;
                    float s = sacc[nt][r];
                    if (col < NTOK) {
                        if (row < NTOK)
                            s += bias_table[rel_idx[row * NTOK + col] * HEADS + h];
                    } else s = -30000.f;
                    sv[nt] = s;
                }
                float m = fmaxf(fmaxf(sv[0], sv[1]), fmaxf(sv[2], sv[3]));
                for (int d = 1; d < 16; d <<= 1) m = fmaxf(m, __shfl_xor(m, d));
                float p[4], sum = 0.f;
                for (int nt = 0; nt < 4; nt++) {
                    p[nt] = exp2f((sv[nt] - m) * 1.4426950408889634f);
                    sum += p[nt];
                }
                for (int d = 1; d < 16; d <<= 1) sum += __shfl_xor(sum, d);
                float inv = 1.f / sum;
                for (int nt = 0; nt < 4; nt++)
                    pp[row * 72 + nt * 16 + l16] = f2bf(p[nt] * inv);
            }
        }
        __syncthreads();
        {
            f4v oacc = (f4v){0.f, 0.f, 0.f, 0.f};
            for (int kb2 = 0; kb2 < 2; kb2++) {
                s8v a  = *(const s8v*)&pp[(mt * 16 + l16) * 72 + kb2 * 32 + quad * 8];
                s8v bf = *(const s8v*)&vs[(half * 16 + l16) * 72 + kb2 * 32 + quad * 8];
                oacc = MFMA16(a, bf, oacc);
            }
            for (int r = 0; r < 4; r++) {
                int row = mt * 16 + quad * 4 + r;
                qs[row * 40 + half * 16 + l16] = f2bf(oacc[r]);
            }
        }
        __syncthreads();
        {
            s8v a = *(const s8v*)&qs[(mt * 16 + l16) * 40 + quad * 8];
            for (int i = 0; i < 6; i++) {
                int ncol = half * 96 + i * 16 + l16;
                s8v bf = ld_bf8(proj_w + ncol * DIM + h * DH + quad * 8);
                acc_p[i] = MFMA16(a, bf, acc_p[i]);
            }
        }
        __syncthreads();
    }
    for (int i = 0; i < 6; i++) {
        int ncol = half * 96 + i * 16 + l16;
        float bias = proj_b[ncol];
        for (int r = 0; r < 4; r++) {
            int row = mt * 16 + quad * 4 + r;
            if (row < NTOK)
                out[((size_t)b * NTOK + row) * DIM + ncol] = acc_p[i][r] + bias;
        }
    }
}

// ============================================================================
extern "C" void kernel_launch(void* const* d_in, const int* in_sizes, int n_in,
                              void* d_out, int out_size, void* d_ws, size_t ws_size,
                              hipStream_t stream) {
    const float* x          = (const float*)d_in[0];
    const float* qkv_w      = (const float*)d_in[1];
    const float* qkv_b      = (const float*)d_in[2];
    const float* proj_w     = (const float*)d_in[3];
    const float* proj_b     = (const float*)d_in[4];
    const float* bias_table = (const float*)d_in[5];
    const int*   rel_idx    = (const int*)d_in[6];
    float*       out        = (float*)d_out;

    const int B_ = in_sizes[0] / (NTOK * DIM);   // 4096

    const size_t FUSED_LDS = 159744;             // 78 KiB x 2 = fits 160 KiB/CU
    static int smem_ok = -1;
    if (smem_ok < 0) {
        smem_ok = (hipFuncSetAttribute((const void*)fused3,
                       hipFuncAttributeMaxDynamicSharedMemorySize,
                       (int)FUSED_LDS) == hipSuccess) ? 1 : 0;
    }

    const size_t sz_wq = (size_t)3 * DIM * DIM * 2;
    const size_t sz_wp = (size_t)DIM * DIM * 2;
    const size_t sz_bm = (size_t)HEADS * NTOK * NTOK * 4;
    const size_t need_fused = sz_wq + sz_wp + sz_bm;

    // split-path workspace layout
    const size_t sz_q  = (size_t)B_ * HEADS * NTOK * DH * 2;
    const size_t sz_k  = sz_q;
    const size_t sz_v  = (size_t)B_ * HEADS * DH * 64 * 2;
    const size_t need_split = sz_q + sz_k + sz_v + sz_wq + sz_wp + sz_bm;

    if (smem_ok == 1 && ws_size >= need_fused) {
        char* p = (char*)d_ws;
        short* wq    = (short*)p;  p += sz_wq;
        short* wp    = (short*)p;  p += sz_wp;
        float* biasM = (float*)p;

        prep_kernel<<<dim3(128), dim3(256), 0, stream>>>(
            qkv_w, proj_w, bias_table, rel_idx, wq, wp, biasM);
        fused3<<<dim3(B_), dim3(512), FUSED_LDS, stream>>>(
            x, wq, qkv_b, wp, proj_b, biasM, out);
    } else if (ws_size >= need_split) {
        char* p = (char*)d_ws;
        short* q_ws  = (short*)p;  p += sz_q;
        short* k_ws  = (short*)p;  p += sz_k;
        short* v_ws  = (short*)p;  p += sz_v;
        short* wq    = (short*)p;  p += sz_wq;
        short* wp    = (short*)p;  p += sz_wp;
        float* biasM = (float*)p;

        prep_kernel<<<dim3(128), dim3(256), 0, stream>>>(
            qkv_w, proj_w, bias_table, rel_idx, wq, wp, biasM);
        qkv_kernel<<<dim3(B_), dim3(512), 0, stream>>>(
            x, wq, qkv_b, q_ws, k_ws, v_ws);
        attn_kernel<<<dim3(B_), dim3(384), 0, stream>>>(
            k_ws, v_ws, biasM, q_ws);
        proj_kernel<<<dim3(B_), dim3(256), 0, stream>>>(
            q_ws, wp, proj_b, out);
    } else {
        winattn_fused<<<dim3(B_), dim3(512), 0, stream>>>(
            x, qkv_w, qkv_b, proj_w, proj_b, bias_table, rel_idx, out);
    }
}